// Round 6
// baseline (2246.975 us; speedup 1.0000x reference)
//
#include <hip/hip_runtime.h>
#include <cstdint>

// ---------------------------------------------------------------------------
// Threefry-2x32, 20 rounds — exact JAX schedule (jax/_src/prng.py)
// ---------------------------------------------------------------------------
static __host__ __device__ inline void tf2x32(uint32_t k0, uint32_t k1,
                                              uint32_t x0, uint32_t x1,
                                              uint32_t &o0, uint32_t &o1) {
  uint32_t ks2 = k0 ^ k1 ^ 0x1BD11BDAu;
  x0 += k0; x1 += k1;
#define TF_R(r) do { x0 += x1; x1 = (x1 << (r)) | (x1 >> (32 - (r))); x1 ^= x0; } while (0)
  TF_R(13); TF_R(15); TF_R(26); TF_R(6);
  x0 += k1; x1 += ks2 + 1u;
  TF_R(17); TF_R(29); TF_R(16); TF_R(24);
  x0 += ks2; x1 += k0 + 2u;
  TF_R(13); TF_R(15); TF_R(26); TF_R(6);
  x0 += k0; x1 += k1 + 3u;
  TF_R(17); TF_R(29); TF_R(16); TF_R(24);
  x0 += k1; x1 += ks2 + 4u;
  TF_R(13); TF_R(15); TF_R(26); TF_R(6);
  x0 += ks2; x1 += k0 + 5u;
#undef TF_R
  o0 = x0; o1 = x1;
}

// XLA's f32 erf_inv expansion (Giles poly, w = -log1p(-x*x)).
__device__ __forceinline__ float erfinv_xla_f32(float x) {
  float w = -log1pf(-x * x);
  float p;
  if (w < 5.0f) {
    w -= 2.5f;
    p = 2.81022636e-08f;
    p = fmaf(p, w, 3.43273939e-07f);
    p = fmaf(p, w, -3.5233877e-06f);
    p = fmaf(p, w, -4.39150654e-06f);
    p = fmaf(p, w, 0.00021858087f);
    p = fmaf(p, w, -0.00125372503f);
    p = fmaf(p, w, -0.00417768164f);
    p = fmaf(p, w, 0.246640727f);
    p = fmaf(p, w, 1.50140941f);
  } else {
    w = sqrtf(w) - 3.0f;
    p = -0.000200214257f;
    p = fmaf(p, w, 0.000100950558f);
    p = fmaf(p, w, 0.00134934322f);
    p = fmaf(p, w, -0.00367342844f);
    p = fmaf(p, w, 0.00573950773f);
    p = fmaf(p, w, -0.0076224613f);
    p = fmaf(p, w, 0.00943887047f);
    p = fmaf(p, w, 1.00167406f);
    p = fmaf(p, w, 2.83297682f);
  }
  return p * x;
}

__device__ __forceinline__ float noise_val(uint32_t kk0, uint32_t kk1, uint32_t idx) {
  uint32_t o0, o1;
  tf2x32(kk0, kk1, 0u, idx, o0, o1);
  uint32_t bits = o0 ^ o1;
  float u01 = __uint_as_float((bits >> 9) | 0x3f800000u) - 1.0f;
  const float LO = -0.99999994f;            // nextafter(-1f, 0f)
  float u = fmaxf(LO, fmaf(u01, 2.0f, LO)); // hi-lo rounds to exactly 2.0f
  return 0.1f * 1.41421356237f * erfinv_xla_f32(u);
}

// ---------------------------------------------------------------------------
// Bucketed edge partition. RPB=128 rows/bucket, bucket = row>>7.
// pack = (row&127)<<17 | col  (needs nn <= 131072).
// ---------------------------------------------------------------------------
#define RPB 128
#define NBMAX 1024
#define EPB 8192   // edges per partition block

__global__ void zerob_k(int* bc, int nb) {
  int i = threadIdx.x;
  if (i < nb) bc[i] = 0;
}

__global__ void bcount_k(const int* __restrict__ row, int* __restrict__ bcount,
                         int ne, int nb) {
  __shared__ int h[NBMAX];
  for (int i = threadIdx.x; i < nb; i += 256) h[i] = 0;
  __syncthreads();
  long base4 = (long)blockIdx.x * (EPB / 4);
  const int4* r4 = (const int4*)row;
  for (int i = 0; i < EPB / 1024; ++i) {
    long e4 = base4 + threadIdx.x + i * 256;
    long e = e4 * 4;
    if (e + 3 < ne) {
      int4 r = r4[e4];
      atomicAdd(&h[r.x >> 7], 1);
      atomicAdd(&h[r.y >> 7], 1);
      atomicAdd(&h[r.z >> 7], 1);
      atomicAdd(&h[r.w >> 7], 1);
    } else {
      for (long q = e; q < ne && q < e + 4; ++q) atomicAdd(&h[row[q] >> 7], 1);
    }
  }
  __syncthreads();
  for (int i = threadIdx.x; i < nb; i += 256) {
    int v = h[i];
    if (v) atomicAdd(&bcount[i], v);
  }
}

// one block, NBMAX threads: exclusive scan -> bbase[nb+1], init bcursor.
__global__ void bscan_k(const int* __restrict__ bcount, int* __restrict__ bbase,
                        int* __restrict__ bcursor, int nb) {
  __shared__ int tmp[NBMAX];
  int t = threadIdx.x;
  int v = (t < nb) ? bcount[t] : 0;
  tmp[t] = v;
  __syncthreads();
  for (int d = 1; d < NBMAX; d <<= 1) {
    int x = (t >= d) ? tmp[t - d] : 0;
    __syncthreads();
    tmp[t] += x;
    __syncthreads();
  }
  int excl = tmp[t] - v;
  if (t < nb) { bbase[t] = excl; bcursor[t] = excl; }
  if (t == nb - 1) bbase[nb] = excl + v;
}

__global__ void bplace_k(const int* __restrict__ row, const int* __restrict__ col,
                         int* __restrict__ bcursor, int* __restrict__ bstore,
                         int ne, int nb) {
  __shared__ int h[NBMAX];
  __shared__ int lcur[NBMAX];
  for (int i = threadIdx.x; i < nb; i += 256) h[i] = 0;
  __syncthreads();
  long base4 = (long)blockIdx.x * (EPB / 4);
  const int4* r4 = (const int4*)row;
  const int4* c4 = (const int4*)col;
  // pass 1: local histogram
  for (int i = 0; i < EPB / 1024; ++i) {
    long e4 = base4 + threadIdx.x + i * 256;
    long e = e4 * 4;
    if (e + 3 < ne) {
      int4 r = r4[e4];
      atomicAdd(&h[r.x >> 7], 1);
      atomicAdd(&h[r.y >> 7], 1);
      atomicAdd(&h[r.z >> 7], 1);
      atomicAdd(&h[r.w >> 7], 1);
    } else {
      for (long q = e; q < ne && q < e + 4; ++q) atomicAdd(&h[row[q] >> 7], 1);
    }
  }
  __syncthreads();
  // reserve contiguous block-local ranges per bucket
  for (int i = threadIdx.x; i < nb; i += 256) {
    int v = h[i];
    lcur[i] = v ? atomicAdd(&bcursor[i], v) : 0;
  }
  __syncthreads();
  // pass 2: place packed edges
  for (int i = 0; i < EPB / 1024; ++i) {
    long e4 = base4 + threadIdx.x + i * 256;
    long e = e4 * 4;
    if (e + 3 < ne) {
      int4 r = r4[e4];
      int4 c = c4[e4];
      int b, p;
      b = r.x >> 7; p = atomicAdd(&lcur[b], 1); bstore[p] = ((r.x & 127) << 17) | c.x;
      b = r.y >> 7; p = atomicAdd(&lcur[b], 1); bstore[p] = ((r.y & 127) << 17) | c.y;
      b = r.z >> 7; p = atomicAdd(&lcur[b], 1); bstore[p] = ((r.z & 127) << 17) | c.z;
      b = r.w >> 7; p = atomicAdd(&lcur[b], 1); bstore[p] = ((r.w & 127) << 17) | c.w;
    } else {
      for (long q = e; q < ne && q < e + 4; ++q) {
        int rr = row[q], cc = col[q];
        int p = atomicAdd(&lcur[rr >> 7], 1);
        bstore[p] = ((rr & 127) << 17) | cc;
      }
    }
  }
}

// ---------------------------------------------------------------------------
// Per-hop fused kernel: one block per bucket (128 rows). Edges accumulate
// into a 32KB LDS tile via ds_add_f32; 8-deep gather pipeline per wave.
// Epilogue: per-row noise (threefry) + L2 norm, written straight to dst.
// ---------------------------------------------------------------------------
__global__ __launch_bounds__(256) void bagg_k(
    const float* __restrict__ src, float* __restrict__ dst,
    const int* __restrict__ bbase, const int* __restrict__ bstore,
    int nn, uint32_t kk0, uint32_t kk1) {
  __shared__ float accs[RPB * 64];  // 32 KB
  for (int i = threadIdx.x; i < RPB * 64; i += 256) accs[i] = 0.f;
  __syncthreads();
  int b = blockIdx.x;
  int r0 = b << 7;
  int beg = bbase[b], end = bbase[b + 1];
  int cnt = end - beg;
  int wv = threadIdx.x >> 6, lane = threadIdx.x & 63;
  for (int base = wv * 64; base < cnt; base += 256) {
    int m = cnt - base; if (m > 64) m = 64;
    int pk = bstore[beg + base + (lane < m ? lane : m - 1)];  // 256B coalesced
    for (int j = 0; j < m; j += 8) {
      float v[8]; int rl[8];
#pragma unroll
      for (int u = 0; u < 8; ++u) {
        int jj = j + u;
        int sl = jj < m ? jj : m - 1;      // clamp -> valid (dup adds 0 below)
        int p = __shfl(pk, sl);
        rl[u] = (p >> 17) & 127;
        int c = p & 0x1FFFF;
        v[u] = src[(size_t)c * 64 + lane]; // 8 independent gathers in flight
      }
#pragma unroll
      for (int u = 0; u < 8; ++u)
        atomicAdd(&accs[rl[u] * 64 + lane], (j + u < m) ? v[u] : 0.f);
    }
  }
  __syncthreads();
  for (int r = wv; r < RPB; r += 4) {
    int gr = r0 + r;
    if (gr >= nn) break;  // monotone per wave
    float a = accs[r * 64 + lane];
    float nv = a + noise_val(kk0, kk1, (uint32_t)(gr * 64 + lane));
    float s = nv * nv;
    for (int d = 1; d < 64; d <<= 1) s += __shfl_xor(s, d);
    float inv = 1.0f / fmaxf(sqrtf(s), 1e-12f);
    dst[(size_t)gr * 64 + lane] = nv * inv;
  }
}

// Row L2-normalize slice 0: 16 lanes/row, float4/lane.
__global__ void l2norm_k(const float4* __restrict__ in, float4* __restrict__ out,
                         int nrows) {
  int t = blockIdx.x * blockDim.x + threadIdx.x;
  int r = t >> 4, l = t & 15;
  if (r >= nrows) return;
  float4 v = in[(size_t)r * 16 + l];
  float s = v.x * v.x + v.y * v.y + v.z * v.z + v.w * v.w;
  s += __shfl_xor(s, 1);
  s += __shfl_xor(s, 2);
  s += __shfl_xor(s, 4);
  s += __shfl_xor(s, 8);
  float inv = 1.0f / fmaxf(sqrtf(s), 1e-12f);
  v.x *= inv; v.y *= inv; v.z *= inv; v.w *= inv;
  out[(size_t)r * 16 + l] = v;
}

// ---------------------------------------------------------------------------
// Fallback (atomic scatter) — used only if bucket path preconditions fail.
// ---------------------------------------------------------------------------
__global__ void noise_fill_k(float* __restrict__ dst, int total,
                             uint32_t kk0, uint32_t kk1) {
  int i = blockIdx.x * blockDim.x + threadIdx.x;
  if (i < total) dst[i] = noise_val(kk0, kk1, (uint32_t)i);
}

__global__ void scatter_k(const int* __restrict__ row, const int* __restrict__ col,
                          const float* __restrict__ src, float* __restrict__ dst,
                          int ne) {
  int t = blockIdx.x * blockDim.x + threadIdx.x;
  int e = t >> 4, l = t & 15;
  if (e >= ne) return;
  int r = row[e], c = col[e];
  float4 v = ((const float4*)(src + (size_t)c * 64))[l];
  float* d = dst + (size_t)r * 64 + (size_t)l * 4;
  atomicAdd(d + 0, v.x);
  atomicAdd(d + 1, v.y);
  atomicAdd(d + 2, v.z);
  atomicAdd(d + 3, v.w);
}

extern "C" void kernel_launch(void* const* d_in, const int* in_sizes, int n_in,
                              void* d_out, int out_size, void* d_ws, size_t ws_size,
                              hipStream_t stream) {
  const float* x = (const float*)d_in[0];
  const int* ei = (const int*)d_in[1];
  float* out = (float*)d_out;

  const int nn = in_sizes[0] / 64;     // 100000
  const int ne = in_sizes[1] / 2;     // 1600000
  const int total = nn * 64;
  const int* row = ei;
  const int* col = ei + ne;

  // Per-hop fold_in keys: threefry2x32((0,42), (0,k)) — host precompute.
  uint32_t fk0[3], fk1[3];
  for (int k = 0; k < 3; ++k) tf2x32(0u, 42u, 0u, (uint32_t)k, fk0[k], fk1[k]);

  const int B = 256;
  const int nb = (nn + RPB - 1) >> 7;          // buckets
  const int nblkE = (ne + EPB - 1) / EPB;      // partition blocks

  // ws (ints): bcount[nb] | bbase[nb+1] | bcursor[nb] | bstore[ne]
  size_t need = ((size_t)nb * 3 + 1 + (size_t)ne) * sizeof(int) + 256;
  bool use_bucket = (nb <= NBMAX) && (nn <= 131072) && (ws_size >= need);

  // out[0] = l2norm(x)
  l2norm_k<<<(nn * 16 + B - 1) / B, B, 0, stream>>>((const float4*)x, (float4*)out, nn);

  if (use_bucket) {
    int* bcount  = (int*)d_ws;
    int* bbase   = bcount + nb;
    int* bcursor = bbase + nb + 1;
    int* bstore  = bcursor + nb;

    zerob_k<<<1, NBMAX, 0, stream>>>(bcount, nb);
    bcount_k<<<nblkE, 256, 0, stream>>>(row, bcount, ne, nb);
    bscan_k<<<1, NBMAX, 0, stream>>>(bcount, bbase, bcursor, nb);
    bplace_k<<<nblkE, 256, 0, stream>>>(row, col, bcursor, bstore, ne, nb);

    for (int k = 0; k < 3; ++k) {
      const float* src = out + (size_t)k * total;
      float* dst = out + (size_t)(k + 1) * total;
      bagg_k<<<nb, 256, 0, stream>>>(src, dst, bbase, bstore, nn, fk0[k], fk1[k]);
    }
  } else {
    for (int k = 0; k < 3; ++k) {
      const float* src = out + (size_t)k * total;
      float* dst = out + (size_t)(k + 1) * total;
      noise_fill_k<<<(total + B - 1) / B, B, 0, stream>>>(dst, total, fk0[k], fk1[k]);
      scatter_k<<<(ne * 16 + B - 1) / B, B, 0, stream>>>(row, col, src, dst, ne);
      l2norm_k<<<(nn * 16 + B - 1) / B, B, 0, stream>>>((const float4*)dst, (float4*)dst, nn);
    }
  }
}

// Round 8
// 292.802 us; speedup vs baseline: 7.6740x; 7.6740x over previous
//
#include <hip/hip_runtime.h>
#include <cstdint>

// ---------------------------------------------------------------------------
// Threefry-2x32, 20 rounds — exact JAX schedule (jax/_src/prng.py)
// ---------------------------------------------------------------------------
static __host__ __device__ inline void tf2x32(uint32_t k0, uint32_t k1,
                                              uint32_t x0, uint32_t x1,
                                              uint32_t &o0, uint32_t &o1) {
  uint32_t ks2 = k0 ^ k1 ^ 0x1BD11BDAu;
  x0 += k0; x1 += k1;
#define TF_R(r) do { x0 += x1; x1 = (x1 << (r)) | (x1 >> (32 - (r))); x1 ^= x0; } while (0)
  TF_R(13); TF_R(15); TF_R(26); TF_R(6);
  x0 += k1; x1 += ks2 + 1u;
  TF_R(17); TF_R(29); TF_R(16); TF_R(24);
  x0 += ks2; x1 += k0 + 2u;
  TF_R(13); TF_R(15); TF_R(26); TF_R(6);
  x0 += k0; x1 += k1 + 3u;
  TF_R(17); TF_R(29); TF_R(16); TF_R(24);
  x0 += k1; x1 += ks2 + 4u;
  TF_R(13); TF_R(15); TF_R(26); TF_R(6);
  x0 += ks2; x1 += k0 + 5u;
#undef TF_R
  o0 = x0; o1 = x1;
}

// XLA's f32 erf_inv expansion (Giles poly, w = -log1p(-x*x)).
__device__ __forceinline__ float erfinv_xla_f32(float x) {
  float w = -log1pf(-x * x);
  float p;
  if (w < 5.0f) {
    w -= 2.5f;
    p = 2.81022636e-08f;
    p = fmaf(p, w, 3.43273939e-07f);
    p = fmaf(p, w, -3.5233877e-06f);
    p = fmaf(p, w, -4.39150654e-06f);
    p = fmaf(p, w, 0.00021858087f);
    p = fmaf(p, w, -0.00125372503f);
    p = fmaf(p, w, -0.00417768164f);
    p = fmaf(p, w, 0.246640727f);
    p = fmaf(p, w, 1.50140941f);
  } else {
    w = sqrtf(w) - 3.0f;
    p = -0.000200214257f;
    p = fmaf(p, w, 0.000100950558f);
    p = fmaf(p, w, 0.00134934322f);
    p = fmaf(p, w, -0.00367342844f);
    p = fmaf(p, w, 0.00573950773f);
    p = fmaf(p, w, -0.0076224613f);
    p = fmaf(p, w, 0.00943887047f);
    p = fmaf(p, w, 1.00167406f);
    p = fmaf(p, w, 2.83297682f);
  }
  return p * x;
}

__device__ __forceinline__ float noise_val(uint32_t kk0, uint32_t kk1, uint32_t idx) {
  uint32_t o0, o1;
  tf2x32(kk0, kk1, 0u, idx, o0, o1);
  uint32_t bits = o0 ^ o1;
  float u01 = __uint_as_float((bits >> 9) | 0x3f800000u) - 1.0f;
  const float LO = -0.99999994f;            // nextafter(-1f, 0f)
  float u = fmaxf(LO, fmaf(u01, 2.0f, LO)); // hi-lo rounds to exactly 2.0f
  return 0.1f * 1.41421356237f * erfinv_xla_f32(u);
}

// ---------------------------------------------------------------------------
// Bucketed edge partition (R6-proven through full timing loop).
// RPB=128 rows/bucket, bucket = row>>7, pack = (row&127)<<17 | col.
// ---------------------------------------------------------------------------
#define RPB 128
#define NBMAX 1024
#define EPB 8192   // edges per partition block

__global__ void zerob_k(int* bc, int nb) {
  int i = threadIdx.x;
  if (i < nb) bc[i] = 0;
}

__global__ void bcount_k(const int* __restrict__ row, int* __restrict__ bcount,
                         int ne, int nb) {
  __shared__ int h[NBMAX];
  for (int i = threadIdx.x; i < nb; i += 256) h[i] = 0;
  __syncthreads();
  long base4 = (long)blockIdx.x * (EPB / 4);
  const int4* r4 = (const int4*)row;
  for (int i = 0; i < EPB / 1024; ++i) {
    long e4 = base4 + threadIdx.x + i * 256;
    long e = e4 * 4;
    if (e + 3 < ne) {
      int4 r = r4[e4];
      atomicAdd(&h[r.x >> 7], 1);
      atomicAdd(&h[r.y >> 7], 1);
      atomicAdd(&h[r.z >> 7], 1);
      atomicAdd(&h[r.w >> 7], 1);
    } else {
      for (long q = e; q < ne && q < e + 4; ++q) atomicAdd(&h[row[q] >> 7], 1);
    }
  }
  __syncthreads();
  for (int i = threadIdx.x; i < nb; i += 256) {
    int v = h[i];
    if (v) atomicAdd(&bcount[i], v);
  }
}

// one block, NBMAX threads: exclusive scan -> bbase[nb+1], init bcursor.
__global__ void bscan_k(const int* __restrict__ bcount, int* __restrict__ bbase,
                        int* __restrict__ bcursor, int nb) {
  __shared__ int tmp[NBMAX];
  int t = threadIdx.x;
  int v = (t < nb) ? bcount[t] : 0;
  tmp[t] = v;
  __syncthreads();
  for (int d = 1; d < NBMAX; d <<= 1) {
    int x = (t >= d) ? tmp[t - d] : 0;
    __syncthreads();
    tmp[t] += x;
    __syncthreads();
  }
  int excl = tmp[t] - v;
  if (t < nb) { bbase[t] = excl; bcursor[t] = excl; }
  if (t == nb - 1) bbase[nb] = excl + v;
}

__global__ void bplace_k(const int* __restrict__ row, const int* __restrict__ col,
                         int* __restrict__ bcursor, int* __restrict__ bstore,
                         int ne, int nb) {
  __shared__ int h[NBMAX];
  __shared__ int lcur[NBMAX];
  for (int i = threadIdx.x; i < nb; i += 256) h[i] = 0;
  __syncthreads();
  long base4 = (long)blockIdx.x * (EPB / 4);
  const int4* r4 = (const int4*)row;
  const int4* c4 = (const int4*)col;
  // pass 1: local histogram
  for (int i = 0; i < EPB / 1024; ++i) {
    long e4 = base4 + threadIdx.x + i * 256;
    long e = e4 * 4;
    if (e + 3 < ne) {
      int4 r = r4[e4];
      atomicAdd(&h[r.x >> 7], 1);
      atomicAdd(&h[r.y >> 7], 1);
      atomicAdd(&h[r.z >> 7], 1);
      atomicAdd(&h[r.w >> 7], 1);
    } else {
      for (long q = e; q < ne && q < e + 4; ++q) atomicAdd(&h[row[q] >> 7], 1);
    }
  }
  __syncthreads();
  // reserve contiguous block-local ranges per bucket
  for (int i = threadIdx.x; i < nb; i += 256) {
    int v = h[i];
    lcur[i] = v ? atomicAdd(&bcursor[i], v) : 0;
  }
  __syncthreads();
  // pass 2: place packed edges
  for (int i = 0; i < EPB / 1024; ++i) {
    long e4 = base4 + threadIdx.x + i * 256;
    long e = e4 * 4;
    if (e + 3 < ne) {
      int4 r = r4[e4];
      int4 c = c4[e4];
      int b, p;
      b = r.x >> 7; p = atomicAdd(&lcur[b], 1); bstore[p] = ((r.x & 127) << 17) | c.x;
      b = r.y >> 7; p = atomicAdd(&lcur[b], 1); bstore[p] = ((r.y & 127) << 17) | c.y;
      b = r.z >> 7; p = atomicAdd(&lcur[b], 1); bstore[p] = ((r.z & 127) << 17) | c.z;
      b = r.w >> 7; p = atomicAdd(&lcur[b], 1); bstore[p] = ((r.w & 127) << 17) | c.w;
    } else {
      for (long q = e; q < ne && q < e + 4; ++q) {
        int rr = row[q], cc = col[q];
        int p = atomicAdd(&lcur[rr >> 7], 1);
        bstore[p] = ((rr & 127) << 17) | cc;
      }
    }
  }
}

// ---------------------------------------------------------------------------
// Per-row counts from bucket-grouped edges: one block per bucket, LDS
// histogram, one plain (deterministic) global write per row. No scans.
// ---------------------------------------------------------------------------
__global__ void rowhist_k(const int* __restrict__ bbase, const int* __restrict__ bstore,
                          int* __restrict__ counts, int nn) {
  __shared__ int h[RPB];
  if (threadIdx.x < RPB) h[threadIdx.x] = 0;
  __syncthreads();
  int b = blockIdx.x;
  int beg = bbase[b], end = bbase[b + 1];
  for (int i = beg + threadIdx.x; i < end; i += 256)
    atomicAdd(&h[(bstore[i] >> 17) & 127], 1);
  __syncthreads();
  if (threadIdx.x < RPB) {
    int gr = (b << 7) + threadIdx.x;
    if (gr < nn) counts[gr] = h[threadIdx.x];
  }
}

// ---------------------------------------------------------------------------
// counts -> offsets/cursor: R3-proven 3-phase global scan chain.
// ---------------------------------------------------------------------------
__global__ void blocksum_k(const int* __restrict__ counts, int* __restrict__ bsum, int n) {
  int i = blockIdx.x * 256 + threadIdx.x;
  int v = (i < n) ? counts[i] : 0;
  for (int d = 1; d < 64; d <<= 1) v += __shfl_xor(v, d);
  __shared__ int ws[4];
  if ((threadIdx.x & 63) == 0) ws[threadIdx.x >> 6] = v;
  __syncthreads();
  if (threadIdx.x == 0) bsum[blockIdx.x] = ws[0] + ws[1] + ws[2] + ws[3];
}

__global__ void scanb_k(int* __restrict__ bsum, int nb) {
  __shared__ int tmp[1024];
  int t = threadIdx.x;
  int v = (t < nb) ? bsum[t] : 0;
  tmp[t] = v;
  __syncthreads();
  for (int d = 1; d < 1024; d <<= 1) {
    int x = (t >= d) ? tmp[t - d] : 0;
    __syncthreads();
    tmp[t] += x;
    __syncthreads();
  }
  if (t < nb) bsum[t] = tmp[t] - v;  // exclusive
}

__global__ void offsets_k(const int* __restrict__ counts, const int* __restrict__ bsumExcl,
                          int* __restrict__ offsets, int* __restrict__ cursor, int n) {
  int i = blockIdx.x * 256 + threadIdx.x;
  int v = (i < n) ? counts[i] : 0;
  __shared__ int tmp[256];
  tmp[threadIdx.x] = v;
  __syncthreads();
  for (int d = 1; d < 256; d <<= 1) {
    int x = (threadIdx.x >= d) ? tmp[threadIdx.x - d] : 0;
    __syncthreads();
    tmp[threadIdx.x] += x;
    __syncthreads();
  }
  int excl = tmp[threadIdx.x] - v + bsumExcl[blockIdx.x];
  if (i < n) { offsets[i] = excl; cursor[i] = excl; }
  if (i == n - 1) offsets[n] = excl + v;
}

// ---------------------------------------------------------------------------
// Bucket-local fill: one block per bucket. Claims cursor[row] (global atomic
// on a hot 512B window) and writes ecol within the bucket's contiguous range
// (lines fully written by one block -> no write amplification). No LDS, no
// scan — trivially simple.
// ---------------------------------------------------------------------------
__global__ void fill2_k(const int* __restrict__ bbase, const int* __restrict__ bstore,
                        int* __restrict__ cursor, int* __restrict__ ecol, int nn) {
  int b = blockIdx.x;
  int beg = bbase[b], end = bbase[b + 1];
  int r0 = b << 7;
  for (int i = beg + threadIdx.x; i < end; i += 256) {
    int p = bstore[i];
    int pos = atomicAdd(&cursor[r0 + ((p >> 17) & 127)], 1);
    ecol[pos] = p & 0x1FFFF;   // raw col, exactly as R3's agg expects
  }
}

// ---------------------------------------------------------------------------
// Fused per-hop kernel — byte-identical to R3's proven agg_k.
// ---------------------------------------------------------------------------
__global__ void agg_k(const float* __restrict__ src, float* __restrict__ dst,
                      const int* __restrict__ offsets, const int* __restrict__ ecol,
                      int nn, uint32_t kk0, uint32_t kk1) {
  int w = (blockIdx.x * blockDim.x + threadIdx.x) >> 6;  // row = wave id
  int lane = threadIdx.x & 63;
  if (w >= nn) return;
  int beg = offsets[w], end = offsets[w + 1];
  int cnt = end - beg;
  float acc = 0.f;
  for (int base = 0; base < cnt; base += 64) {
    int m = cnt - base; if (m > 64) m = 64;
    int idx = base + lane;
    int myc = ecol[beg + (idx < cnt ? idx : cnt - 1)];
    for (int j = 0; j < m; j += 8) {
      float v[8];
#pragma unroll
      for (int u = 0; u < 8; ++u) {
        int jj = j + u;
        int sl = jj < m ? jj : m - 1;        // uniform clamp -> valid address
        int c = __shfl(myc, sl);
        v[u] = src[(size_t)c * 64 + lane];   // 8 independent gathers in flight
      }
#pragma unroll
      for (int u = 0; u < 8; ++u)
        acc += (j + u < m) ? v[u] : 0.f;
    }
  }
  float nv = acc + noise_val(kk0, kk1, (uint32_t)(w * 64 + lane));
  float s = nv * nv;
  for (int d = 1; d < 64; d <<= 1) s += __shfl_xor(s, d);
  float inv = 1.0f / fmaxf(sqrtf(s), 1e-12f);
  dst[(size_t)w * 64 + lane] = nv * inv;
}

// Row L2-normalize slice 0: 16 lanes/row, float4/lane.
__global__ void l2norm_k(const float4* __restrict__ in, float4* __restrict__ out,
                         int nrows) {
  int t = blockIdx.x * blockDim.x + threadIdx.x;
  int r = t >> 4, l = t & 15;
  if (r >= nrows) return;
  float4 v = in[(size_t)r * 16 + l];
  float s = v.x * v.x + v.y * v.y + v.z * v.z + v.w * v.w;
  s += __shfl_xor(s, 1);
  s += __shfl_xor(s, 2);
  s += __shfl_xor(s, 4);
  s += __shfl_xor(s, 8);
  float inv = 1.0f / fmaxf(sqrtf(s), 1e-12f);
  v.x *= inv; v.y *= inv; v.z *= inv; v.w *= inv;
  out[(size_t)r * 16 + l] = v;
}

// ---------------------------------------------------------------------------
// Fallback (atomic scatter) — used only if bucket path preconditions fail.
// ---------------------------------------------------------------------------
__global__ void noise_fill_k(float* __restrict__ dst, int total,
                             uint32_t kk0, uint32_t kk1) {
  int i = blockIdx.x * blockDim.x + threadIdx.x;
  if (i < total) dst[i] = noise_val(kk0, kk1, (uint32_t)i);
}

__global__ void scatter_k(const int* __restrict__ row, const int* __restrict__ col,
                          const float* __restrict__ src, float* __restrict__ dst,
                          int ne) {
  int t = blockIdx.x * blockDim.x + threadIdx.x;
  int e = t >> 4, l = t & 15;
  if (e >= ne) return;
  int r = row[e], c = col[e];
  float4 v = ((const float4*)(src + (size_t)c * 64))[l];
  float* d = dst + (size_t)r * 64 + (size_t)l * 4;
  atomicAdd(d + 0, v.x);
  atomicAdd(d + 1, v.y);
  atomicAdd(d + 2, v.z);
  atomicAdd(d + 3, v.w);
}

extern "C" void kernel_launch(void* const* d_in, const int* in_sizes, int n_in,
                              void* d_out, int out_size, void* d_ws, size_t ws_size,
                              hipStream_t stream) {
  const float* x = (const float*)d_in[0];
  const int* ei = (const int*)d_in[1];
  float* out = (float*)d_out;

  const int nn = in_sizes[0] / 64;     // 100000
  const int ne = in_sizes[1] / 2;     // 1600000
  const int total = nn * 64;
  const int* row = ei;
  const int* col = ei + ne;

  // Per-hop fold_in keys: threefry2x32((0,42), (0,k)) — host precompute.
  uint32_t fk0[3], fk1[3];
  for (int k = 0; k < 3; ++k) tf2x32(0u, 42u, 0u, (uint32_t)k, fk0[k], fk1[k]);

  const int B = 256;
  const int nb = (nn + RPB - 1) >> 7;          // buckets
  const int nblkE = (ne + EPB - 1) / EPB;      // partition blocks
  const int nb2 = (nn + 255) / 256;            // scan blocks over rows

  // ws (ints): bcount[nb] | bbase[nb+1] | bcursor[nb] | counts[nn]
  //          | offsets[nn+1] | cursor[nn] | bsum[1024] | bstore[ne] | ecol[ne]
  size_t need = ((size_t)nb * 3 + 1 + (size_t)nn * 3 + 1 + 1024 + 2 * (size_t)ne)
                * sizeof(int) + 256;
  bool use_bucket = (nb <= NBMAX) && (nn <= 131072) && (nb2 <= 1024) && (ws_size >= need);

  // out[0] = l2norm(x)
  l2norm_k<<<(nn * 16 + B - 1) / B, B, 0, stream>>>((const float4*)x, (float4*)out, nn);

  if (use_bucket) {
    int* bcount  = (int*)d_ws;
    int* bbase   = bcount + nb;
    int* bcursor = bbase + nb + 1;
    int* counts  = bcursor + nb;
    int* offsets = counts + nn;
    int* cursor  = offsets + nn + 1;
    int* bsum    = cursor + nn;
    int* bstore  = bsum + 1024;
    int* ecol    = bstore + ne;

    // bucket partition (R6-proven)
    zerob_k<<<1, NBMAX, 0, stream>>>(bcount, nb);
    bcount_k<<<nblkE, 256, 0, stream>>>(row, bcount, ne, nb);
    bscan_k<<<1, NBMAX, 0, stream>>>(bcount, bbase, bcursor, nb);
    bplace_k<<<nblkE, 256, 0, stream>>>(row, col, bcursor, bstore, ne, nb);
    // per-row counts (deterministic) + R3-proven scan -> offsets/cursor
    rowhist_k<<<nb, 256, 0, stream>>>(bbase, bstore, counts, nn);
    blocksum_k<<<nb2, 256, 0, stream>>>(counts, bsum, nn);
    scanb_k<<<1, 1024, 0, stream>>>(bsum, nb2);
    offsets_k<<<nb2, 256, 0, stream>>>(counts, bsum, offsets, cursor, nn);
    // bucket-local row grouping
    fill2_k<<<nb, 256, 0, stream>>>(bbase, bstore, cursor, ecol, nn);

    for (int k = 0; k < 3; ++k) {
      const float* src = out + (size_t)k * total;
      float* dst = out + (size_t)(k + 1) * total;
      agg_k<<<(nn * 64 + B - 1) / B, B, 0, stream>>>(src, dst, offsets, ecol,
                                                     nn, fk0[k], fk1[k]);
    }
  } else {
    for (int k = 0; k < 3; ++k) {
      const float* src = out + (size_t)k * total;
      float* dst = out + (size_t)(k + 1) * total;
      noise_fill_k<<<(total + B - 1) / B, B, 0, stream>>>(dst, total, fk0[k], fk1[k]);
      scatter_k<<<(ne * 16 + B - 1) / B, B, 0, stream>>>(row, col, src, dst, ne);
      l2norm_k<<<(nn * 16 + B - 1) / B, B, 0, stream>>>((const float4*)dst, (float4*)dst, nn);
    }
  }
}

// Round 9
// 275.821 us; speedup vs baseline: 8.1465x; 1.0616x over previous
//
#include <hip/hip_runtime.h>
#include <cstdint>

// ---------------------------------------------------------------------------
// Threefry-2x32, 20 rounds — exact JAX schedule (jax/_src/prng.py)
// ---------------------------------------------------------------------------
static __host__ __device__ inline void tf2x32(uint32_t k0, uint32_t k1,
                                              uint32_t x0, uint32_t x1,
                                              uint32_t &o0, uint32_t &o1) {
  uint32_t ks2 = k0 ^ k1 ^ 0x1BD11BDAu;
  x0 += k0; x1 += k1;
#define TF_R(r) do { x0 += x1; x1 = (x1 << (r)) | (x1 >> (32 - (r))); x1 ^= x0; } while (0)
  TF_R(13); TF_R(15); TF_R(26); TF_R(6);
  x0 += k1; x1 += ks2 + 1u;
  TF_R(17); TF_R(29); TF_R(16); TF_R(24);
  x0 += ks2; x1 += k0 + 2u;
  TF_R(13); TF_R(15); TF_R(26); TF_R(6);
  x0 += k0; x1 += k1 + 3u;
  TF_R(17); TF_R(29); TF_R(16); TF_R(24);
  x0 += k1; x1 += ks2 + 4u;
  TF_R(13); TF_R(15); TF_R(26); TF_R(6);
  x0 += ks2; x1 += k0 + 5u;
#undef TF_R
  o0 = x0; o1 = x1;
}

// XLA's f32 erf_inv expansion (Giles poly, w = -log1p(-x*x)).
__device__ __forceinline__ float erfinv_xla_f32(float x) {
  float w = -log1pf(-x * x);
  float p;
  if (w < 5.0f) {
    w -= 2.5f;
    p = 2.81022636e-08f;
    p = fmaf(p, w, 3.43273939e-07f);
    p = fmaf(p, w, -3.5233877e-06f);
    p = fmaf(p, w, -4.39150654e-06f);
    p = fmaf(p, w, 0.00021858087f);
    p = fmaf(p, w, -0.00125372503f);
    p = fmaf(p, w, -0.00417768164f);
    p = fmaf(p, w, 0.246640727f);
    p = fmaf(p, w, 1.50140941f);
  } else {
    w = sqrtf(w) - 3.0f;
    p = -0.000200214257f;
    p = fmaf(p, w, 0.000100950558f);
    p = fmaf(p, w, 0.00134934322f);
    p = fmaf(p, w, -0.00367342844f);
    p = fmaf(p, w, 0.00573950773f);
    p = fmaf(p, w, -0.0076224613f);
    p = fmaf(p, w, 0.00943887047f);
    p = fmaf(p, w, 1.00167406f);
    p = fmaf(p, w, 2.83297682f);
  }
  return p * x;
}

__device__ __forceinline__ float noise_val(uint32_t kk0, uint32_t kk1, uint32_t idx) {
  uint32_t o0, o1;
  tf2x32(kk0, kk1, 0u, idx, o0, o1);
  uint32_t bits = o0 ^ o1;
  float u01 = __uint_as_float((bits >> 9) | 0x3f800000u) - 1.0f;
  const float LO = -0.99999994f;            // nextafter(-1f, 0f)
  float u = fmaxf(LO, fmaf(u01, 2.0f, LO)); // hi-lo rounds to exactly 2.0f
  return 0.1f * 1.41421356237f * erfinv_xla_f32(u);
}

// ---------------------------------------------------------------------------
// Bucketed edge partition (R6/R8-proven through full timing loop).
// RPB=128 rows/bucket, bucket = row>>7, pack = (row&127)<<17 | col.
// ---------------------------------------------------------------------------
#define RPB 128
#define NBMAX 1024
#define EPB 8192   // edges per partition block

__global__ void zerob_k(int* bc, int nb) {
  int i = threadIdx.x;
  if (i < nb) bc[i] = 0;
}

__global__ void bcount_k(const int* __restrict__ row, int* __restrict__ bcount,
                         int ne, int nb) {
  __shared__ int h[NBMAX];
  for (int i = threadIdx.x; i < nb; i += 256) h[i] = 0;
  __syncthreads();
  long base4 = (long)blockIdx.x * (EPB / 4);
  const int4* r4 = (const int4*)row;
  for (int i = 0; i < EPB / 1024; ++i) {
    long e4 = base4 + threadIdx.x + i * 256;
    long e = e4 * 4;
    if (e + 3 < ne) {
      int4 r = r4[e4];
      atomicAdd(&h[r.x >> 7], 1);
      atomicAdd(&h[r.y >> 7], 1);
      atomicAdd(&h[r.z >> 7], 1);
      atomicAdd(&h[r.w >> 7], 1);
    } else {
      for (long q = e; q < ne && q < e + 4; ++q) atomicAdd(&h[row[q] >> 7], 1);
    }
  }
  __syncthreads();
  for (int i = threadIdx.x; i < nb; i += 256) {
    int v = h[i];
    if (v) atomicAdd(&bcount[i], v);
  }
}

// one block, NBMAX threads: exclusive scan -> bbase[nb+1], init bcursor.
__global__ void bscan_k(const int* __restrict__ bcount, int* __restrict__ bbase,
                        int* __restrict__ bcursor, int nb) {
  __shared__ int tmp[NBMAX];
  int t = threadIdx.x;
  int v = (t < nb) ? bcount[t] : 0;
  tmp[t] = v;
  __syncthreads();
  for (int d = 1; d < NBMAX; d <<= 1) {
    int x = (t >= d) ? tmp[t - d] : 0;
    __syncthreads();
    tmp[t] += x;
    __syncthreads();
  }
  int excl = tmp[t] - v;
  if (t < nb) { bbase[t] = excl; bcursor[t] = excl; }
  if (t == nb - 1) bbase[nb] = excl + v;
}

__global__ void bplace_k(const int* __restrict__ row, const int* __restrict__ col,
                         int* __restrict__ bcursor, int* __restrict__ bstore,
                         int ne, int nb) {
  __shared__ int h[NBMAX];
  __shared__ int lcur[NBMAX];
  for (int i = threadIdx.x; i < nb; i += 256) h[i] = 0;
  __syncthreads();
  long base4 = (long)blockIdx.x * (EPB / 4);
  const int4* r4 = (const int4*)row;
  const int4* c4 = (const int4*)col;
  // pass 1: local histogram
  for (int i = 0; i < EPB / 1024; ++i) {
    long e4 = base4 + threadIdx.x + i * 256;
    long e = e4 * 4;
    if (e + 3 < ne) {
      int4 r = r4[e4];
      atomicAdd(&h[r.x >> 7], 1);
      atomicAdd(&h[r.y >> 7], 1);
      atomicAdd(&h[r.z >> 7], 1);
      atomicAdd(&h[r.w >> 7], 1);
    } else {
      for (long q = e; q < ne && q < e + 4; ++q) atomicAdd(&h[row[q] >> 7], 1);
    }
  }
  __syncthreads();
  // reserve contiguous block-local ranges per bucket
  for (int i = threadIdx.x; i < nb; i += 256) {
    int v = h[i];
    lcur[i] = v ? atomicAdd(&bcursor[i], v) : 0;
  }
  __syncthreads();
  // pass 2: place packed edges
  for (int i = 0; i < EPB / 1024; ++i) {
    long e4 = base4 + threadIdx.x + i * 256;
    long e = e4 * 4;
    if (e + 3 < ne) {
      int4 r = r4[e4];
      int4 c = c4[e4];
      int b, p;
      b = r.x >> 7; p = atomicAdd(&lcur[b], 1); bstore[p] = ((r.x & 127) << 17) | c.x;
      b = r.y >> 7; p = atomicAdd(&lcur[b], 1); bstore[p] = ((r.y & 127) << 17) | c.y;
      b = r.z >> 7; p = atomicAdd(&lcur[b], 1); bstore[p] = ((r.z & 127) << 17) | c.z;
      b = r.w >> 7; p = atomicAdd(&lcur[b], 1); bstore[p] = ((r.w & 127) << 17) | c.w;
    } else {
      for (long q = e; q < ne && q < e + 4; ++q) {
        int rr = row[q], cc = col[q];
        int p = atomicAdd(&lcur[rr >> 7], 1);
        bstore[p] = ((rr & 127) << 17) | cc;
      }
    }
  }
}

// ---------------------------------------------------------------------------
// Per-row counts from bucket-grouped edges (R8-proven).
// ---------------------------------------------------------------------------
__global__ void rowhist_k(const int* __restrict__ bbase, const int* __restrict__ bstore,
                          int* __restrict__ counts, int nn) {
  __shared__ int h[RPB];
  if (threadIdx.x < RPB) h[threadIdx.x] = 0;
  __syncthreads();
  int b = blockIdx.x;
  int beg = bbase[b], end = bbase[b + 1];
  for (int i = beg + threadIdx.x; i < end; i += 256)
    atomicAdd(&h[(bstore[i] >> 17) & 127], 1);
  __syncthreads();
  if (threadIdx.x < RPB) {
    int gr = (b << 7) + threadIdx.x;
    if (gr < nn) counts[gr] = h[threadIdx.x];
  }
}

// ---------------------------------------------------------------------------
// counts -> offsets/cursor: R3-proven 3-phase global scan chain.
// ---------------------------------------------------------------------------
__global__ void blocksum_k(const int* __restrict__ counts, int* __restrict__ bsum, int n) {
  int i = blockIdx.x * 256 + threadIdx.x;
  int v = (i < n) ? counts[i] : 0;
  for (int d = 1; d < 64; d <<= 1) v += __shfl_xor(v, d);
  __shared__ int ws[4];
  if ((threadIdx.x & 63) == 0) ws[threadIdx.x >> 6] = v;
  __syncthreads();
  if (threadIdx.x == 0) bsum[blockIdx.x] = ws[0] + ws[1] + ws[2] + ws[3];
}

__global__ void scanb_k(int* __restrict__ bsum, int nb) {
  __shared__ int tmp[1024];
  int t = threadIdx.x;
  int v = (t < nb) ? bsum[t] : 0;
  tmp[t] = v;
  __syncthreads();
  for (int d = 1; d < 1024; d <<= 1) {
    int x = (t >= d) ? tmp[t - d] : 0;
    __syncthreads();
    tmp[t] += x;
    __syncthreads();
  }
  if (t < nb) bsum[t] = tmp[t] - v;  // exclusive
}

__global__ void offsets_k(const int* __restrict__ counts, const int* __restrict__ bsumExcl,
                          int* __restrict__ offsets, int* __restrict__ cursor, int n) {
  int i = blockIdx.x * 256 + threadIdx.x;
  int v = (i < n) ? counts[i] : 0;
  __shared__ int tmp[256];
  tmp[threadIdx.x] = v;
  __syncthreads();
  for (int d = 1; d < 256; d <<= 1) {
    int x = (threadIdx.x >= d) ? tmp[threadIdx.x - d] : 0;
    __syncthreads();
    tmp[threadIdx.x] += x;
    __syncthreads();
  }
  int excl = tmp[threadIdx.x] - v + bsumExcl[blockIdx.x];
  if (i < n) { offsets[i] = excl; cursor[i] = excl; }
  if (i == n - 1) offsets[n] = excl + v;
}

// ---------------------------------------------------------------------------
// Bucket-local fill (R8-proven).
// ---------------------------------------------------------------------------
__global__ void fill2_k(const int* __restrict__ bbase, const int* __restrict__ bstore,
                        int* __restrict__ cursor, int* __restrict__ ecol, int nn) {
  int b = blockIdx.x;
  int beg = bbase[b], end = bbase[b + 1];
  int r0 = b << 7;
  for (int i = beg + threadIdx.x; i < end; i += 256) {
    int p = bstore[i];
    int pos = atomicAdd(&cursor[r0 + ((p >> 17) & 127)], 1);
    ecol[pos] = p & 0x1FFFF;
  }
}

// ---------------------------------------------------------------------------
// Per-hop kernel v3: one wave per dest row. Edge-list walk is wave-uniform,
// so indices go through the SCALAR pipes: readfirstlane(beg) -> ecol loads
// become s_load, col*64 address math becomes SALU (saddr), gather is
// global_load_dword v, v(lane*4), s[pair]. Full 8-groups have NO clamp and
// NO predication (pure v_add_f32); one clamped+predicated tail per row.
// ---------------------------------------------------------------------------
__global__ void agg_k(const float* __restrict__ src, float* __restrict__ dst,
                      const int* __restrict__ offsets, const int* __restrict__ ecol,
                      int nn, uint32_t kk0, uint32_t kk1) {
  int w = (blockIdx.x * blockDim.x + threadIdx.x) >> 6;  // row = wave id
  int lane = threadIdx.x & 63;
  if (w >= nn) return;
  int beg = __builtin_amdgcn_readfirstlane(offsets[w]);
  int end = __builtin_amdgcn_readfirstlane(offsets[w + 1]);
  int cnt = end - beg;
  float acc0 = 0.f, acc1 = 0.f;
  int full = cnt & ~7;
  for (int j = 0; j < full; j += 8) {
    int c[8];
#pragma unroll
    for (int u = 0; u < 8; ++u)
      c[u] = ecol[beg + j + u];              // scalar s_load (uniform addr)
    float v[8];
#pragma unroll
    for (int u = 0; u < 8; ++u)
      v[u] = src[(size_t)c[u] * 64 + lane];  // saddr gather, voffset=lane*4
#pragma unroll
    for (int u = 0; u < 8; ++u) {
      if (u & 1) acc1 += v[u]; else acc0 += v[u];
    }
  }
  int rem = cnt - full;
  if (rem) {
    int cb = beg + full;
    float v[8];
#pragma unroll
    for (int u = 0; u < 8; ++u) {
      int uu = u < rem ? u : rem - 1;        // scalar clamp -> valid address
      int c = ecol[cb + uu];                 // scalar s_load
      v[u] = src[(size_t)c * 64 + lane];
    }
#pragma unroll
    for (int u = 0; u < 8; ++u) {
      float z = (u < rem) ? v[u] : 0.f;
      if (u & 1) acc1 += z; else acc0 += z;
    }
  }
  float acc = acc0 + acc1;
  float nv = acc + noise_val(kk0, kk1, (uint32_t)(w * 64 + lane));
  float s = nv * nv;
  for (int d = 1; d < 64; d <<= 1) s += __shfl_xor(s, d);
  float inv = 1.0f / fmaxf(sqrtf(s), 1e-12f);
  dst[(size_t)w * 64 + lane] = nv * inv;
}

// Row L2-normalize slice 0: 16 lanes/row, float4/lane.
__global__ void l2norm_k(const float4* __restrict__ in, float4* __restrict__ out,
                         int nrows) {
  int t = blockIdx.x * blockDim.x + threadIdx.x;
  int r = t >> 4, l = t & 15;
  if (r >= nrows) return;
  float4 v = in[(size_t)r * 16 + l];
  float s = v.x * v.x + v.y * v.y + v.z * v.z + v.w * v.w;
  s += __shfl_xor(s, 1);
  s += __shfl_xor(s, 2);
  s += __shfl_xor(s, 4);
  s += __shfl_xor(s, 8);
  float inv = 1.0f / fmaxf(sqrtf(s), 1e-12f);
  v.x *= inv; v.y *= inv; v.z *= inv; v.w *= inv;
  out[(size_t)r * 16 + l] = v;
}

// ---------------------------------------------------------------------------
// Fallback (atomic scatter) — used only if bucket path preconditions fail.
// ---------------------------------------------------------------------------
__global__ void noise_fill_k(float* __restrict__ dst, int total,
                             uint32_t kk0, uint32_t kk1) {
  int i = blockIdx.x * blockDim.x + threadIdx.x;
  if (i < total) dst[i] = noise_val(kk0, kk1, (uint32_t)i);
}

__global__ void scatter_k(const int* __restrict__ row, const int* __restrict__ col,
                          const float* __restrict__ src, float* __restrict__ dst,
                          int ne) {
  int t = blockIdx.x * blockDim.x + threadIdx.x;
  int e = t >> 4, l = t & 15;
  if (e >= ne) return;
  int r = row[e], c = col[e];
  float4 v = ((const float4*)(src + (size_t)c * 64))[l];
  float* d = dst + (size_t)r * 64 + (size_t)l * 4;
  atomicAdd(d + 0, v.x);
  atomicAdd(d + 1, v.y);
  atomicAdd(d + 2, v.z);
  atomicAdd(d + 3, v.w);
}

extern "C" void kernel_launch(void* const* d_in, const int* in_sizes, int n_in,
                              void* d_out, int out_size, void* d_ws, size_t ws_size,
                              hipStream_t stream) {
  const float* x = (const float*)d_in[0];
  const int* ei = (const int*)d_in[1];
  float* out = (float*)d_out;

  const int nn = in_sizes[0] / 64;     // 100000
  const int ne = in_sizes[1] / 2;     // 1600000
  const int total = nn * 64;
  const int* row = ei;
  const int* col = ei + ne;

  // Per-hop fold_in keys: threefry2x32((0,42), (0,k)) — host precompute.
  uint32_t fk0[3], fk1[3];
  for (int k = 0; k < 3; ++k) tf2x32(0u, 42u, 0u, (uint32_t)k, fk0[k], fk1[k]);

  const int B = 256;
  const int nb = (nn + RPB - 1) >> 7;          // buckets
  const int nblkE = (ne + EPB - 1) / EPB;      // partition blocks
  const int nb2 = (nn + 255) / 256;            // scan blocks over rows

  // ws (ints): bcount[nb] | bbase[nb+1] | bcursor[nb] | counts[nn]
  //          | offsets[nn+1] | cursor[nn] | bsum[1024] | bstore[ne] | ecol[ne]
  size_t need = ((size_t)nb * 3 + 1 + (size_t)nn * 3 + 1 + 1024 + 2 * (size_t)ne)
                * sizeof(int) + 256;
  bool use_bucket = (nb <= NBMAX) && (nn <= 131072) && (nb2 <= 1024) && (ws_size >= need);

  // out[0] = l2norm(x)
  l2norm_k<<<(nn * 16 + B - 1) / B, B, 0, stream>>>((const float4*)x, (float4*)out, nn);

  if (use_bucket) {
    int* bcount  = (int*)d_ws;
    int* bbase   = bcount + nb;
    int* bcursor = bbase + nb + 1;
    int* counts  = bcursor + nb;
    int* offsets = counts + nn;
    int* cursor  = offsets + nn + 1;
    int* bsum    = cursor + nn;
    int* bstore  = bsum + 1024;
    int* ecol    = bstore + ne;

    // bucket partition (R6-proven)
    zerob_k<<<1, NBMAX, 0, stream>>>(bcount, nb);
    bcount_k<<<nblkE, 256, 0, stream>>>(row, bcount, ne, nb);
    bscan_k<<<1, NBMAX, 0, stream>>>(bcount, bbase, bcursor, nb);
    bplace_k<<<nblkE, 256, 0, stream>>>(row, col, bcursor, bstore, ne, nb);
    // per-row counts (deterministic) + R3-proven scan -> offsets/cursor
    rowhist_k<<<nb, 256, 0, stream>>>(bbase, bstore, counts, nn);
    blocksum_k<<<nb2, 256, 0, stream>>>(counts, bsum, nn);
    scanb_k<<<1, 1024, 0, stream>>>(bsum, nb2);
    offsets_k<<<nb2, 256, 0, stream>>>(counts, bsum, offsets, cursor, nn);
    // bucket-local row grouping
    fill2_k<<<nb, 256, 0, stream>>>(bbase, bstore, cursor, ecol, nn);

    for (int k = 0; k < 3; ++k) {
      const float* src = out + (size_t)k * total;
      float* dst = out + (size_t)(k + 1) * total;
      agg_k<<<(nn * 64 + B - 1) / B, B, 0, stream>>>(src, dst, offsets, ecol,
                                                     nn, fk0[k], fk1[k]);
    }
  } else {
    for (int k = 0; k < 3; ++k) {
      const float* src = out + (size_t)k * total;
      float* dst = out + (size_t)(k + 1) * total;
      noise_fill_k<<<(total + B - 1) / B, B, 0, stream>>>(dst, total, fk0[k], fk1[k]);
      scatter_k<<<(ne * 16 + B - 1) / B, B, 0, stream>>>(row, col, src, dst, ne);
      l2norm_k<<<(nn * 16 + B - 1) / B, B, 0, stream>>>((const float4*)dst, (float4*)dst, nn);
    }
  }
}

// Round 10
// 270.966 us; speedup vs baseline: 8.2925x; 1.0179x over previous
//
#include <hip/hip_runtime.h>
#include <cstdint>

// ---------------------------------------------------------------------------
// Threefry-2x32, 20 rounds — exact JAX schedule (jax/_src/prng.py)
// ---------------------------------------------------------------------------
static __host__ __device__ inline void tf2x32(uint32_t k0, uint32_t k1,
                                              uint32_t x0, uint32_t x1,
                                              uint32_t &o0, uint32_t &o1) {
  uint32_t ks2 = k0 ^ k1 ^ 0x1BD11BDAu;
  x0 += k0; x1 += k1;
#define TF_R(r) do { x0 += x1; x1 = (x1 << (r)) | (x1 >> (32 - (r))); x1 ^= x0; } while (0)
  TF_R(13); TF_R(15); TF_R(26); TF_R(6);
  x0 += k1; x1 += ks2 + 1u;
  TF_R(17); TF_R(29); TF_R(16); TF_R(24);
  x0 += ks2; x1 += k0 + 2u;
  TF_R(13); TF_R(15); TF_R(26); TF_R(6);
  x0 += k0; x1 += k1 + 3u;
  TF_R(17); TF_R(29); TF_R(16); TF_R(24);
  x0 += k1; x1 += ks2 + 4u;
  TF_R(13); TF_R(15); TF_R(26); TF_R(6);
  x0 += ks2; x1 += k0 + 5u;
#undef TF_R
  o0 = x0; o1 = x1;
}

// XLA's f32 erf_inv expansion (Giles poly, w = -log1p(-x*x)).
__device__ __forceinline__ float erfinv_xla_f32(float x) {
  float w = -log1pf(-x * x);
  float p;
  if (w < 5.0f) {
    w -= 2.5f;
    p = 2.81022636e-08f;
    p = fmaf(p, w, 3.43273939e-07f);
    p = fmaf(p, w, -3.5233877e-06f);
    p = fmaf(p, w, -4.39150654e-06f);
    p = fmaf(p, w, 0.00021858087f);
    p = fmaf(p, w, -0.00125372503f);
    p = fmaf(p, w, -0.00417768164f);
    p = fmaf(p, w, 0.246640727f);
    p = fmaf(p, w, 1.50140941f);
  } else {
    w = sqrtf(w) - 3.0f;
    p = -0.000200214257f;
    p = fmaf(p, w, 0.000100950558f);
    p = fmaf(p, w, 0.00134934322f);
    p = fmaf(p, w, -0.00367342844f);
    p = fmaf(p, w, 0.00573950773f);
    p = fmaf(p, w, -0.0076224613f);
    p = fmaf(p, w, 0.00943887047f);
    p = fmaf(p, w, 1.00167406f);
    p = fmaf(p, w, 2.83297682f);
  }
  return p * x;
}

__device__ __forceinline__ float noise_val(uint32_t kk0, uint32_t kk1, uint32_t idx) {
  uint32_t o0, o1;
  tf2x32(kk0, kk1, 0u, idx, o0, o1);
  uint32_t bits = o0 ^ o1;
  float u01 = __uint_as_float((bits >> 9) | 0x3f800000u) - 1.0f;
  const float LO = -0.99999994f;            // nextafter(-1f, 0f)
  float u = fmaxf(LO, fmaf(u01, 2.0f, LO)); // hi-lo rounds to exactly 2.0f
  return 0.1f * 1.41421356237f * erfinv_xla_f32(u);
}

// ---------------------------------------------------------------------------
// Bucketed edge partition (R6/R8-proven through full timing loop).
// RPB=128 rows/bucket, bucket = row>>7, pack = (row&127)<<17 | col.
// ---------------------------------------------------------------------------
#define RPB 128
#define NBMAX 1024
#define EPB 8192   // edges per partition block

__global__ void zerob_k(int* bc, int nb) {
  int i = threadIdx.x;
  if (i < nb) bc[i] = 0;
}

__global__ void bcount_k(const int* __restrict__ row, int* __restrict__ bcount,
                         int ne, int nb) {
  __shared__ int h[NBMAX];
  for (int i = threadIdx.x; i < nb; i += 256) h[i] = 0;
  __syncthreads();
  long base4 = (long)blockIdx.x * (EPB / 4);
  const int4* r4 = (const int4*)row;
  for (int i = 0; i < EPB / 1024; ++i) {
    long e4 = base4 + threadIdx.x + i * 256;
    long e = e4 * 4;
    if (e + 3 < ne) {
      int4 r = r4[e4];
      atomicAdd(&h[r.x >> 7], 1);
      atomicAdd(&h[r.y >> 7], 1);
      atomicAdd(&h[r.z >> 7], 1);
      atomicAdd(&h[r.w >> 7], 1);
    } else {
      for (long q = e; q < ne && q < e + 4; ++q) atomicAdd(&h[row[q] >> 7], 1);
    }
  }
  __syncthreads();
  for (int i = threadIdx.x; i < nb; i += 256) {
    int v = h[i];
    if (v) atomicAdd(&bcount[i], v);
  }
}

// one block, NBMAX threads: exclusive scan -> bbase[nb+1], init bcursor.
__global__ void bscan_k(const int* __restrict__ bcount, int* __restrict__ bbase,
                        int* __restrict__ bcursor, int nb) {
  __shared__ int tmp[NBMAX];
  int t = threadIdx.x;
  int v = (t < nb) ? bcount[t] : 0;
  tmp[t] = v;
  __syncthreads();
  for (int d = 1; d < NBMAX; d <<= 1) {
    int x = (t >= d) ? tmp[t - d] : 0;
    __syncthreads();
    tmp[t] += x;
    __syncthreads();
  }
  int excl = tmp[t] - v;
  if (t < nb) { bbase[t] = excl; bcursor[t] = excl; }
  if (t == nb - 1) bbase[nb] = excl + v;
}

__global__ void bplace_k(const int* __restrict__ row, const int* __restrict__ col,
                         int* __restrict__ bcursor, int* __restrict__ bstore,
                         int ne, int nb) {
  __shared__ int h[NBMAX];
  __shared__ int lcur[NBMAX];
  for (int i = threadIdx.x; i < nb; i += 256) h[i] = 0;
  __syncthreads();
  long base4 = (long)blockIdx.x * (EPB / 4);
  const int4* r4 = (const int4*)row;
  const int4* c4 = (const int4*)col;
  // pass 1: local histogram
  for (int i = 0; i < EPB / 1024; ++i) {
    long e4 = base4 + threadIdx.x + i * 256;
    long e = e4 * 4;
    if (e + 3 < ne) {
      int4 r = r4[e4];
      atomicAdd(&h[r.x >> 7], 1);
      atomicAdd(&h[r.y >> 7], 1);
      atomicAdd(&h[r.z >> 7], 1);
      atomicAdd(&h[r.w >> 7], 1);
    } else {
      for (long q = e; q < ne && q < e + 4; ++q) atomicAdd(&h[row[q] >> 7], 1);
    }
  }
  __syncthreads();
  // reserve contiguous block-local ranges per bucket
  for (int i = threadIdx.x; i < nb; i += 256) {
    int v = h[i];
    lcur[i] = v ? atomicAdd(&bcursor[i], v) : 0;
  }
  __syncthreads();
  // pass 2: place packed edges
  for (int i = 0; i < EPB / 1024; ++i) {
    long e4 = base4 + threadIdx.x + i * 256;
    long e = e4 * 4;
    if (e + 3 < ne) {
      int4 r = r4[e4];
      int4 c = c4[e4];
      int b, p;
      b = r.x >> 7; p = atomicAdd(&lcur[b], 1); bstore[p] = ((r.x & 127) << 17) | c.x;
      b = r.y >> 7; p = atomicAdd(&lcur[b], 1); bstore[p] = ((r.y & 127) << 17) | c.y;
      b = r.z >> 7; p = atomicAdd(&lcur[b], 1); bstore[p] = ((r.z & 127) << 17) | c.z;
      b = r.w >> 7; p = atomicAdd(&lcur[b], 1); bstore[p] = ((r.w & 127) << 17) | c.w;
    } else {
      for (long q = e; q < ne && q < e + 4; ++q) {
        int rr = row[q], cc = col[q];
        int p = atomicAdd(&lcur[rr >> 7], 1);
        bstore[p] = ((rr & 127) << 17) | cc;
      }
    }
  }
}

// ---------------------------------------------------------------------------
// Per-row counts from bucket-grouped edges (R8-proven).
// ---------------------------------------------------------------------------
__global__ void rowhist_k(const int* __restrict__ bbase, const int* __restrict__ bstore,
                          int* __restrict__ counts, int nn) {
  __shared__ int h[RPB];
  if (threadIdx.x < RPB) h[threadIdx.x] = 0;
  __syncthreads();
  int b = blockIdx.x;
  int beg = bbase[b], end = bbase[b + 1];
  for (int i = beg + threadIdx.x; i < end; i += 256)
    atomicAdd(&h[(bstore[i] >> 17) & 127], 1);
  __syncthreads();
  if (threadIdx.x < RPB) {
    int gr = (b << 7) + threadIdx.x;
    if (gr < nn) counts[gr] = h[threadIdx.x];
  }
}

// ---------------------------------------------------------------------------
// counts -> offsets/cursor: R3-proven 3-phase global scan chain.
// ---------------------------------------------------------------------------
__global__ void blocksum_k(const int* __restrict__ counts, int* __restrict__ bsum, int n) {
  int i = blockIdx.x * 256 + threadIdx.x;
  int v = (i < n) ? counts[i] : 0;
  for (int d = 1; d < 64; d <<= 1) v += __shfl_xor(v, d);
  __shared__ int ws[4];
  if ((threadIdx.x & 63) == 0) ws[threadIdx.x >> 6] = v;
  __syncthreads();
  if (threadIdx.x == 0) bsum[blockIdx.x] = ws[0] + ws[1] + ws[2] + ws[3];
}

__global__ void scanb_k(int* __restrict__ bsum, int nb) {
  __shared__ int tmp[1024];
  int t = threadIdx.x;
  int v = (t < nb) ? bsum[t] : 0;
  tmp[t] = v;
  __syncthreads();
  for (int d = 1; d < 1024; d <<= 1) {
    int x = (t >= d) ? tmp[t - d] : 0;
    __syncthreads();
    tmp[t] += x;
    __syncthreads();
  }
  if (t < nb) bsum[t] = tmp[t] - v;  // exclusive
}

__global__ void offsets_k(const int* __restrict__ counts, const int* __restrict__ bsumExcl,
                          int* __restrict__ offsets, int* __restrict__ cursor, int n) {
  int i = blockIdx.x * 256 + threadIdx.x;
  int v = (i < n) ? counts[i] : 0;
  __shared__ int tmp[256];
  tmp[threadIdx.x] = v;
  __syncthreads();
  for (int d = 1; d < 256; d <<= 1) {
    int x = (threadIdx.x >= d) ? tmp[threadIdx.x - d] : 0;
    __syncthreads();
    tmp[threadIdx.x] += x;
    __syncthreads();
  }
  int excl = tmp[threadIdx.x] - v + bsumExcl[blockIdx.x];
  if (i < n) { offsets[i] = excl; cursor[i] = excl; }
  if (i == n - 1) offsets[n] = excl + v;
}

// ---------------------------------------------------------------------------
// Bucket-local fill (R8-proven).
// ---------------------------------------------------------------------------
__global__ void fill2_k(const int* __restrict__ bbase, const int* __restrict__ bstore,
                        int* __restrict__ cursor, int* __restrict__ ecol, int nn) {
  int b = blockIdx.x;
  int beg = bbase[b], end = bbase[b + 1];
  int r0 = b << 7;
  for (int i = beg + threadIdx.x; i < end; i += 256) {
    int p = bstore[i];
    int pos = atomicAdd(&cursor[r0 + ((p >> 17) & 127)], 1);
    ecol[pos] = p & 0x1FFFF;
  }
}

// ---------------------------------------------------------------------------
// Per-hop kernel v4: one wave per dest row. Lane split g=lane>>4 (edge slot),
// f=lane&15 (feature quad). One global_load_dwordx4 covers a full 256B row
// with 16 lanes -> 4 edges per VMEM instruction. 16-edge steps (R4's 32-edge
// rounding waste fixed). Epilogue: reduce over g, float4->scalar redistribute
// (4 shfl + selects, no runtime vector index), 1 threefry/lane, L2 norm.
// ---------------------------------------------------------------------------
__global__ void agg_k(const float* __restrict__ src, float* __restrict__ dst,
                      const int* __restrict__ offsets, const int* __restrict__ ecol,
                      int nn, uint32_t kk0, uint32_t kk1) {
  int w = (blockIdx.x * blockDim.x + threadIdx.x) >> 6;  // row = wave id
  int lane = threadIdx.x & 63;
  int g = lane >> 4, f = lane & 15;
  if (w >= nn) return;
  const float4* src4 = (const float4*)src;
  int beg = __builtin_amdgcn_readfirstlane(offsets[w]);
  int end = __builtin_amdgcn_readfirstlane(offsets[w + 1]);
  int cnt = end - beg;
  float4 acc = make_float4(0.f, 0.f, 0.f, 0.f);
  for (int base = 0; base < cnt; base += 64) {
    int m = cnt - base; if (m > 64) m = 64;
    int idx = base + lane;
    int myc = ecol[beg + (idx < cnt ? idx : cnt - 1)];   // 256B coalesced preload
    for (int j = 0; j < m; j += 16) {      // 16 edges per step, 4 gathers in flight
      float4 v[4];
#pragma unroll
      for (int u = 0; u < 4; ++u) {
        int jj = j + u * 4 + g;
        int sl = jj < m ? jj : m - 1;      // clamp -> valid address
        int c = __shfl(myc, sl);
        v[u] = src4[(size_t)c * 16 + f];   // 4 edges per dwordx4 instr
      }
#pragma unroll
      for (int u = 0; u < 4; ++u) {
        int jj = j + u * 4 + g;
        bool ok = jj < m;
        acc.x += ok ? v[u].x : 0.f;
        acc.y += ok ? v[u].y : 0.f;
        acc.z += ok ? v[u].z : 0.f;
        acc.w += ok ? v[u].w : 0.f;
      }
    }
  }
  // reduce over the 4 edge-groups (lanes differing in bits 4,5)
  acc.x += __shfl_xor(acc.x, 16); acc.x += __shfl_xor(acc.x, 32);
  acc.y += __shfl_xor(acc.y, 16); acc.y += __shfl_xor(acc.y, 32);
  acc.z += __shfl_xor(acc.z, 16); acc.z += __shfl_xor(acc.z, 32);
  acc.w += __shfl_xor(acc.w, 16); acc.w += __shfl_xor(acc.w, 32);
  // redistribute: lane wants feature `lane` = fq*4 + q, held as acc[q] on lane fq
  int fq = lane >> 2, q = lane & 3;
  float vx = __shfl(acc.x, fq);
  float vy = __shfl(acc.y, fq);
  float vz = __shfl(acc.z, fq);
  float vw = __shfl(acc.w, fq);
  float a = (q < 2) ? (q == 0 ? vx : vy) : (q == 2 ? vz : vw);
  float nv = a + noise_val(kk0, kk1, (uint32_t)(w * 64 + lane));
  float s = nv * nv;
  for (int d = 1; d < 64; d <<= 1) s += __shfl_xor(s, d);
  float inv = 1.0f / fmaxf(sqrtf(s), 1e-12f);
  dst[(size_t)w * 64 + lane] = nv * inv;
}

// Row L2-normalize slice 0: 16 lanes/row, float4/lane.
__global__ void l2norm_k(const float4* __restrict__ in, float4* __restrict__ out,
                         int nrows) {
  int t = blockIdx.x * blockDim.x + threadIdx.x;
  int r = t >> 4, l = t & 15;
  if (r >= nrows) return;
  float4 v = in[(size_t)r * 16 + l];
  float s = v.x * v.x + v.y * v.y + v.z * v.z + v.w * v.w;
  s += __shfl_xor(s, 1);
  s += __shfl_xor(s, 2);
  s += __shfl_xor(s, 4);
  s += __shfl_xor(s, 8);
  float inv = 1.0f / fmaxf(sqrtf(s), 1e-12f);
  v.x *= inv; v.y *= inv; v.z *= inv; v.w *= inv;
  out[(size_t)r * 16 + l] = v;
}

// ---------------------------------------------------------------------------
// Fallback (atomic scatter) — used only if bucket path preconditions fail.
// ---------------------------------------------------------------------------
__global__ void noise_fill_k(float* __restrict__ dst, int total,
                             uint32_t kk0, uint32_t kk1) {
  int i = blockIdx.x * blockDim.x + threadIdx.x;
  if (i < total) dst[i] = noise_val(kk0, kk1, (uint32_t)i);
}

__global__ void scatter_k(const int* __restrict__ row, const int* __restrict__ col,
                          const float* __restrict__ src, float* __restrict__ dst,
                          int ne) {
  int t = blockIdx.x * blockDim.x + threadIdx.x;
  int e = t >> 4, l = t & 15;
  if (e >= ne) return;
  int r = row[e], c = col[e];
  float4 v = ((const float4*)(src + (size_t)c * 64))[l];
  float* d = dst + (size_t)r * 64 + (size_t)l * 4;
  atomicAdd(d + 0, v.x);
  atomicAdd(d + 1, v.y);
  atomicAdd(d + 2, v.z);
  atomicAdd(d + 3, v.w);
}

extern "C" void kernel_launch(void* const* d_in, const int* in_sizes, int n_in,
                              void* d_out, int out_size, void* d_ws, size_t ws_size,
                              hipStream_t stream) {
  const float* x = (const float*)d_in[0];
  const int* ei = (const int*)d_in[1];
  float* out = (float*)d_out;

  const int nn = in_sizes[0] / 64;     // 100000
  const int ne = in_sizes[1] / 2;     // 1600000
  const int total = nn * 64;
  const int* row = ei;
  const int* col = ei + ne;

  // Per-hop fold_in keys: threefry2x32((0,42), (0,k)) — host precompute.
  uint32_t fk0[3], fk1[3];
  for (int k = 0; k < 3; ++k) tf2x32(0u, 42u, 0u, (uint32_t)k, fk0[k], fk1[k]);

  const int B = 256;
  const int nb = (nn + RPB - 1) >> 7;          // buckets
  const int nblkE = (ne + EPB - 1) / EPB;      // partition blocks
  const int nb2 = (nn + 255) / 256;            // scan blocks over rows

  // ws (ints): bcount[nb] | bbase[nb+1] | bcursor[nb] | counts[nn]
  //          | offsets[nn+1] | cursor[nn] | bsum[1024] | bstore[ne] | ecol[ne]
  size_t need = ((size_t)nb * 3 + 1 + (size_t)nn * 3 + 1 + 1024 + 2 * (size_t)ne)
                * sizeof(int) + 256;
  bool use_bucket = (nb <= NBMAX) && (nn <= 131072) && (nb2 <= 1024) && (ws_size >= need);

  // out[0] = l2norm(x)
  l2norm_k<<<(nn * 16 + B - 1) / B, B, 0, stream>>>((const float4*)x, (float4*)out, nn);

  if (use_bucket) {
    int* bcount  = (int*)d_ws;
    int* bbase   = bcount + nb;
    int* bcursor = bbase + nb + 1;
    int* counts  = bcursor + nb;
    int* offsets = counts + nn;
    int* cursor  = offsets + nn + 1;
    int* bsum    = cursor + nn;
    int* bstore  = bsum + 1024;
    int* ecol    = bstore + ne;

    // bucket partition (R6-proven)
    zerob_k<<<1, NBMAX, 0, stream>>>(bcount, nb);
    bcount_k<<<nblkE, 256, 0, stream>>>(row, bcount, ne, nb);
    bscan_k<<<1, NBMAX, 0, stream>>>(bcount, bbase, bcursor, nb);
    bplace_k<<<nblkE, 256, 0, stream>>>(row, col, bcursor, bstore, ne, nb);
    // per-row counts (deterministic) + R3-proven scan -> offsets/cursor
    rowhist_k<<<nb, 256, 0, stream>>>(bbase, bstore, counts, nn);
    blocksum_k<<<nb2, 256, 0, stream>>>(counts, bsum, nn);
    scanb_k<<<1, 1024, 0, stream>>>(bsum, nb2);
    offsets_k<<<nb2, 256, 0, stream>>>(counts, bsum, offsets, cursor, nn);
    // bucket-local row grouping
    fill2_k<<<nb, 256, 0, stream>>>(bbase, bstore, cursor, ecol, nn);

    for (int k = 0; k < 3; ++k) {
      const float* src = out + (size_t)k * total;
      float* dst = out + (size_t)(k + 1) * total;
      agg_k<<<(nn * 64 + B - 1) / B, B, 0, stream>>>(src, dst, offsets, ecol,
                                                     nn, fk0[k], fk1[k]);
    }
  } else {
    for (int k = 0; k < 3; ++k) {
      const float* src = out + (size_t)k * total;
      float* dst = out + (size_t)(k + 1) * total;
      noise_fill_k<<<(total + B - 1) / B, B, 0, stream>>>(dst, total, fk0[k], fk1[k]);
      scatter_k<<<(ne * 16 + B - 1) / B, B, 0, stream>>>(row, col, src, dst, ne);
      l2norm_k<<<(nn * 16 + B - 1) / B, B, 0, stream>>>((const float4*)dst, (float4*)dst, nn);
    }
  }
}

// Round 11
// 265.315 us; speedup vs baseline: 8.4691x; 1.0213x over previous
//
#include <hip/hip_runtime.h>
#include <cstdint>

// ---------------------------------------------------------------------------
// Threefry-2x32, 20 rounds — exact JAX schedule (jax/_src/prng.py)
// ---------------------------------------------------------------------------
static __host__ __device__ inline void tf2x32(uint32_t k0, uint32_t k1,
                                              uint32_t x0, uint32_t x1,
                                              uint32_t &o0, uint32_t &o1) {
  uint32_t ks2 = k0 ^ k1 ^ 0x1BD11BDAu;
  x0 += k0; x1 += k1;
#define TF_R(r) do { x0 += x1; x1 = (x1 << (r)) | (x1 >> (32 - (r))); x1 ^= x0; } while (0)
  TF_R(13); TF_R(15); TF_R(26); TF_R(6);
  x0 += k1; x1 += ks2 + 1u;
  TF_R(17); TF_R(29); TF_R(16); TF_R(24);
  x0 += ks2; x1 += k0 + 2u;
  TF_R(13); TF_R(15); TF_R(26); TF_R(6);
  x0 += k0; x1 += k1 + 3u;
  TF_R(17); TF_R(29); TF_R(16); TF_R(24);
  x0 += k1; x1 += ks2 + 4u;
  TF_R(13); TF_R(15); TF_R(26); TF_R(6);
  x0 += ks2; x1 += k0 + 5u;
#undef TF_R
  o0 = x0; o1 = x1;
}

// XLA's f32 erf_inv expansion (Giles poly, w = -log1p(-x*x)).
__device__ __forceinline__ float erfinv_xla_f32(float x) {
  float w = -log1pf(-x * x);
  float p;
  if (w < 5.0f) {
    w -= 2.5f;
    p = 2.81022636e-08f;
    p = fmaf(p, w, 3.43273939e-07f);
    p = fmaf(p, w, -3.5233877e-06f);
    p = fmaf(p, w, -4.39150654e-06f);
    p = fmaf(p, w, 0.00021858087f);
    p = fmaf(p, w, -0.00125372503f);
    p = fmaf(p, w, -0.00417768164f);
    p = fmaf(p, w, 0.246640727f);
    p = fmaf(p, w, 1.50140941f);
  } else {
    w = sqrtf(w) - 3.0f;
    p = -0.000200214257f;
    p = fmaf(p, w, 0.000100950558f);
    p = fmaf(p, w, 0.00134934322f);
    p = fmaf(p, w, -0.00367342844f);
    p = fmaf(p, w, 0.00573950773f);
    p = fmaf(p, w, -0.0076224613f);
    p = fmaf(p, w, 0.00943887047f);
    p = fmaf(p, w, 1.00167406f);
    p = fmaf(p, w, 2.83297682f);
  }
  return p * x;
}

__device__ __forceinline__ float noise_val(uint32_t kk0, uint32_t kk1, uint32_t idx) {
  uint32_t o0, o1;
  tf2x32(kk0, kk1, 0u, idx, o0, o1);
  uint32_t bits = o0 ^ o1;
  float u01 = __uint_as_float((bits >> 9) | 0x3f800000u) - 1.0f;
  const float LO = -0.99999994f;            // nextafter(-1f, 0f)
  float u = fmaxf(LO, fmaf(u01, 2.0f, LO)); // hi-lo rounds to exactly 2.0f
  return 0.1f * 1.41421356237f * erfinv_xla_f32(u);
}

// ---------------------------------------------------------------------------
// Bucketed edge partition (R6/R8/R10-proven through full timing loop).
// RPB=128 rows/bucket, bucket = row>>7, pack = (row&127)<<17 | col.
// ---------------------------------------------------------------------------
#define RPB 128
#define NBMAX 1024
#define EPB 8192   // edges per partition block

__global__ void zerob_k(int* bc, int nb) {
  int i = threadIdx.x;
  if (i < nb) bc[i] = 0;
}

__global__ void bcount_k(const int* __restrict__ row, int* __restrict__ bcount,
                         int ne, int nb) {
  __shared__ int h[NBMAX];
  for (int i = threadIdx.x; i < nb; i += 256) h[i] = 0;
  __syncthreads();
  long base4 = (long)blockIdx.x * (EPB / 4);
  const int4* r4 = (const int4*)row;
  for (int i = 0; i < EPB / 1024; ++i) {
    long e4 = base4 + threadIdx.x + i * 256;
    long e = e4 * 4;
    if (e + 3 < ne) {
      int4 r = r4[e4];
      atomicAdd(&h[r.x >> 7], 1);
      atomicAdd(&h[r.y >> 7], 1);
      atomicAdd(&h[r.z >> 7], 1);
      atomicAdd(&h[r.w >> 7], 1);
    } else {
      for (long q = e; q < ne && q < e + 4; ++q) atomicAdd(&h[row[q] >> 7], 1);
    }
  }
  __syncthreads();
  for (int i = threadIdx.x; i < nb; i += 256) {
    int v = h[i];
    if (v) atomicAdd(&bcount[i], v);
  }
}

// one block, NBMAX threads: exclusive scan -> bbase[nb+1], init bcursor.
__global__ void bscan_k(const int* __restrict__ bcount, int* __restrict__ bbase,
                        int* __restrict__ bcursor, int nb) {
  __shared__ int tmp[NBMAX];
  int t = threadIdx.x;
  int v = (t < nb) ? bcount[t] : 0;
  tmp[t] = v;
  __syncthreads();
  for (int d = 1; d < NBMAX; d <<= 1) {
    int x = (t >= d) ? tmp[t - d] : 0;
    __syncthreads();
    tmp[t] += x;
    __syncthreads();
  }
  int excl = tmp[t] - v;
  if (t < nb) { bbase[t] = excl; bcursor[t] = excl; }
  if (t == nb - 1) bbase[nb] = excl + v;
}

__global__ void bplace_k(const int* __restrict__ row, const int* __restrict__ col,
                         int* __restrict__ bcursor, int* __restrict__ bstore,
                         int ne, int nb) {
  __shared__ int h[NBMAX];
  __shared__ int lcur[NBMAX];
  for (int i = threadIdx.x; i < nb; i += 256) h[i] = 0;
  __syncthreads();
  long base4 = (long)blockIdx.x * (EPB / 4);
  const int4* r4 = (const int4*)row;
  const int4* c4 = (const int4*)col;
  // pass 1: local histogram
  for (int i = 0; i < EPB / 1024; ++i) {
    long e4 = base4 + threadIdx.x + i * 256;
    long e = e4 * 4;
    if (e + 3 < ne) {
      int4 r = r4[e4];
      atomicAdd(&h[r.x >> 7], 1);
      atomicAdd(&h[r.y >> 7], 1);
      atomicAdd(&h[r.z >> 7], 1);
      atomicAdd(&h[r.w >> 7], 1);
    } else {
      for (long q = e; q < ne && q < e + 4; ++q) atomicAdd(&h[row[q] >> 7], 1);
    }
  }
  __syncthreads();
  // reserve contiguous block-local ranges per bucket
  for (int i = threadIdx.x; i < nb; i += 256) {
    int v = h[i];
    lcur[i] = v ? atomicAdd(&bcursor[i], v) : 0;
  }
  __syncthreads();
  // pass 2: place packed edges
  for (int i = 0; i < EPB / 1024; ++i) {
    long e4 = base4 + threadIdx.x + i * 256;
    long e = e4 * 4;
    if (e + 3 < ne) {
      int4 r = r4[e4];
      int4 c = c4[e4];
      int b, p;
      b = r.x >> 7; p = atomicAdd(&lcur[b], 1); bstore[p] = ((r.x & 127) << 17) | c.x;
      b = r.y >> 7; p = atomicAdd(&lcur[b], 1); bstore[p] = ((r.y & 127) << 17) | c.y;
      b = r.z >> 7; p = atomicAdd(&lcur[b], 1); bstore[p] = ((r.z & 127) << 17) | c.z;
      b = r.w >> 7; p = atomicAdd(&lcur[b], 1); bstore[p] = ((r.w & 127) << 17) | c.w;
    } else {
      for (long q = e; q < ne && q < e + 4; ++q) {
        int rr = row[q], cc = col[q];
        int p = atomicAdd(&lcur[rr >> 7], 1);
        bstore[p] = ((rr & 127) << 17) | cc;
      }
    }
  }
}

// ---------------------------------------------------------------------------
// Per-bucket row offsets: LDS histogram + 128-wide LDS scan (separate h/sc
// buffers, bscan-pattern guards), then offsets[gr]=cursor[gr]=bbase[b]+excl.
// Replaces the R8 rowhist+blocksum+scanb+offsets global chain (the global
// scan was redundant: bbase already carries the inter-bucket prefix).
// ---------------------------------------------------------------------------
__global__ __launch_bounds__(256) void rowoff_k(
    const int* __restrict__ bbase, const int* __restrict__ bstore,
    int* __restrict__ offsets, int* __restrict__ cursor, int nn, int nb) {
  __shared__ int h[RPB];
  __shared__ int sc[RPB];
  int t = threadIdx.x;
  int b = blockIdx.x;
  int beg = bbase[b], end = bbase[b + 1];
  if (t < RPB) h[t] = 0;
  __syncthreads();
  for (int i = beg + t; i < end; i += 256)
    atomicAdd(&h[(bstore[i] >> 17) & 127], 1);
  __syncthreads();
  if (t < RPB) sc[t] = h[t];
  __syncthreads();
  for (int d = 1; d < RPB; d <<= 1) {
    int v = 0;
    if (t < RPB && t >= d) v = sc[t - d];
    __syncthreads();
    if (t < RPB) sc[t] += v;
    __syncthreads();
  }
  if (t < RPB) {
    int excl = sc[t] - h[t];          // exclusive within bucket
    int gr = (b << 7) + t;
    if (gr < nn) {
      offsets[gr] = beg + excl;
      cursor[gr]  = beg + excl;
    }
  }
  if (b == nb - 1 && t == 0) offsets[nn] = end;
}

// ---------------------------------------------------------------------------
// Bucket-local fill (R8-proven): claims cursor[row], writes ecol within the
// bucket's contiguous range.
// ---------------------------------------------------------------------------
__global__ void fill2_k(const int* __restrict__ bbase, const int* __restrict__ bstore,
                        int* __restrict__ cursor, int* __restrict__ ecol, int nn) {
  int b = blockIdx.x;
  int beg = bbase[b], end = bbase[b + 1];
  int r0 = b << 7;
  for (int i = beg + threadIdx.x; i < end; i += 256) {
    int p = bstore[i];
    int pos = atomicAdd(&cursor[r0 + ((p >> 17) & 127)], 1);
    ecol[pos] = p & 0x1FFFF;
  }
}

// ---------------------------------------------------------------------------
// Per-hop kernel (R10): one wave per dest row, g=lane>>4 edge slot, f=lane&15
// feature quad; one dwordx4 covers a 256B row with 16 lanes -> 4 edges/instr.
// ---------------------------------------------------------------------------
__global__ void agg_k(const float* __restrict__ src, float* __restrict__ dst,
                      const int* __restrict__ offsets, const int* __restrict__ ecol,
                      int nn, uint32_t kk0, uint32_t kk1) {
  int w = (blockIdx.x * blockDim.x + threadIdx.x) >> 6;  // row = wave id
  int lane = threadIdx.x & 63;
  int g = lane >> 4, f = lane & 15;
  if (w >= nn) return;
  const float4* src4 = (const float4*)src;
  int beg = __builtin_amdgcn_readfirstlane(offsets[w]);
  int end = __builtin_amdgcn_readfirstlane(offsets[w + 1]);
  int cnt = end - beg;
  float4 acc = make_float4(0.f, 0.f, 0.f, 0.f);
  for (int base = 0; base < cnt; base += 64) {
    int m = cnt - base; if (m > 64) m = 64;
    int idx = base + lane;
    int myc = ecol[beg + (idx < cnt ? idx : cnt - 1)];   // 256B coalesced preload
    for (int j = 0; j < m; j += 16) {      // 16 edges per step, 4 gathers in flight
      float4 v[4];
#pragma unroll
      for (int u = 0; u < 4; ++u) {
        int jj = j + u * 4 + g;
        int sl = jj < m ? jj : m - 1;      // clamp -> valid address
        int c = __shfl(myc, sl);
        v[u] = src4[(size_t)c * 16 + f];   // 4 edges per dwordx4 instr
      }
#pragma unroll
      for (int u = 0; u < 4; ++u) {
        int jj = j + u * 4 + g;
        bool ok = jj < m;
        acc.x += ok ? v[u].x : 0.f;
        acc.y += ok ? v[u].y : 0.f;
        acc.z += ok ? v[u].z : 0.f;
        acc.w += ok ? v[u].w : 0.f;
      }
    }
  }
  // reduce over the 4 edge-groups (lanes differing in bits 4,5)
  acc.x += __shfl_xor(acc.x, 16); acc.x += __shfl_xor(acc.x, 32);
  acc.y += __shfl_xor(acc.y, 16); acc.y += __shfl_xor(acc.y, 32);
  acc.z += __shfl_xor(acc.z, 16); acc.z += __shfl_xor(acc.z, 32);
  acc.w += __shfl_xor(acc.w, 16); acc.w += __shfl_xor(acc.w, 32);
  // redistribute: lane wants feature `lane` = fq*4 + q, held as acc[q] on lane fq
  int fq = lane >> 2, q = lane & 3;
  float vx = __shfl(acc.x, fq);
  float vy = __shfl(acc.y, fq);
  float vz = __shfl(acc.z, fq);
  float vw = __shfl(acc.w, fq);
  float a = (q < 2) ? (q == 0 ? vx : vy) : (q == 2 ? vz : vw);
  float nv = a + noise_val(kk0, kk1, (uint32_t)(w * 64 + lane));
  float s = nv * nv;
  for (int d = 1; d < 64; d <<= 1) s += __shfl_xor(s, d);
  float inv = 1.0f / fmaxf(sqrtf(s), 1e-12f);
  dst[(size_t)w * 64 + lane] = nv * inv;
}

// Row L2-normalize slice 0: 16 lanes/row, float4/lane.
__global__ void l2norm_k(const float4* __restrict__ in, float4* __restrict__ out,
                         int nrows) {
  int t = blockIdx.x * blockDim.x + threadIdx.x;
  int r = t >> 4, l = t & 15;
  if (r >= nrows) return;
  float4 v = in[(size_t)r * 16 + l];
  float s = v.x * v.x + v.y * v.y + v.z * v.z + v.w * v.w;
  s += __shfl_xor(s, 1);
  s += __shfl_xor(s, 2);
  s += __shfl_xor(s, 4);
  s += __shfl_xor(s, 8);
  float inv = 1.0f / fmaxf(sqrtf(s), 1e-12f);
  v.x *= inv; v.y *= inv; v.z *= inv; v.w *= inv;
  out[(size_t)r * 16 + l] = v;
}

// ---------------------------------------------------------------------------
// Fallback (atomic scatter) — used only if bucket path preconditions fail.
// ---------------------------------------------------------------------------
__global__ void noise_fill_k(float* __restrict__ dst, int total,
                             uint32_t kk0, uint32_t kk1) {
  int i = blockIdx.x * blockDim.x + threadIdx.x;
  if (i < total) dst[i] = noise_val(kk0, kk1, (uint32_t)i);
}

__global__ void scatter_k(const int* __restrict__ row, const int* __restrict__ col,
                          const float* __restrict__ src, float* __restrict__ dst,
                          int ne) {
  int t = blockIdx.x * blockDim.x + threadIdx.x;
  int e = t >> 4, l = t & 15;
  if (e >= ne) return;
  int r = row[e], c = col[e];
  float4 v = ((const float4*)(src + (size_t)c * 64))[l];
  float* d = dst + (size_t)r * 64 + (size_t)l * 4;
  atomicAdd(d + 0, v.x);
  atomicAdd(d + 1, v.y);
  atomicAdd(d + 2, v.z);
  atomicAdd(d + 3, v.w);
}

extern "C" void kernel_launch(void* const* d_in, const int* in_sizes, int n_in,
                              void* d_out, int out_size, void* d_ws, size_t ws_size,
                              hipStream_t stream) {
  const float* x = (const float*)d_in[0];
  const int* ei = (const int*)d_in[1];
  float* out = (float*)d_out;

  const int nn = in_sizes[0] / 64;     // 100000
  const int ne = in_sizes[1] / 2;     // 1600000
  const int total = nn * 64;
  const int* row = ei;
  const int* col = ei + ne;

  // Per-hop fold_in keys: threefry2x32((0,42), (0,k)) — host precompute.
  uint32_t fk0[3], fk1[3];
  for (int k = 0; k < 3; ++k) tf2x32(0u, 42u, 0u, (uint32_t)k, fk0[k], fk1[k]);

  const int B = 256;
  const int nb = (nn + RPB - 1) >> 7;          // buckets
  const int nblkE = (ne + EPB - 1) / EPB;      // partition blocks

  // ws (ints): bcount[nb] | bbase[nb+1] | bcursor[nb] | offsets[nn+1]
  //          | cursor[nn] | bstore[ne] | ecol[ne]
  size_t need = ((size_t)nb * 3 + 1 + (size_t)nn * 2 + 1 + 2 * (size_t)ne)
                * sizeof(int) + 256;
  bool use_bucket = (nb <= NBMAX) && (nn <= 131072) && (ws_size >= need);

  // out[0] = l2norm(x)
  l2norm_k<<<(nn * 16 + B - 1) / B, B, 0, stream>>>((const float4*)x, (float4*)out, nn);

  if (use_bucket) {
    int* bcount  = (int*)d_ws;
    int* bbase   = bcount + nb;
    int* bcursor = bbase + nb + 1;
    int* offsets = bcursor + nb;
    int* cursor  = offsets + nn + 1;
    int* bstore  = cursor + nn;
    int* ecol    = bstore + ne;

    // bucket partition (R6-proven)
    zerob_k<<<1, NBMAX, 0, stream>>>(bcount, nb);
    bcount_k<<<nblkE, 256, 0, stream>>>(row, bcount, ne, nb);
    bscan_k<<<1, NBMAX, 0, stream>>>(bcount, bbase, bcursor, nb);
    bplace_k<<<nblkE, 256, 0, stream>>>(row, col, bcursor, bstore, ne, nb);
    // per-bucket row offsets (replaces rowhist+blocksum+scanb+offsets)
    rowoff_k<<<nb, 256, 0, stream>>>(bbase, bstore, offsets, cursor, nn, nb);
    // bucket-local row grouping (R8-proven)
    fill2_k<<<nb, 256, 0, stream>>>(bbase, bstore, cursor, ecol, nn);

    for (int k = 0; k < 3; ++k) {
      const float* src = out + (size_t)k * total;
      float* dst = out + (size_t)(k + 1) * total;
      agg_k<<<(nn * 64 + B - 1) / B, B, 0, stream>>>(src, dst, offsets, ecol,
                                                     nn, fk0[k], fk1[k]);
    }
  } else {
    for (int k = 0; k < 3; ++k) {
      const float* src = out + (size_t)k * total;
      float* dst = out + (size_t)(k + 1) * total;
      noise_fill_k<<<(total + B - 1) / B, B, 0, stream>>>(dst, total, fk0[k], fk1[k]);
      scatter_k<<<(ne * 16 + B - 1) / B, B, 0, stream>>>(row, col, src, dst, ne);
      l2norm_k<<<(nn * 16 + B - 1) / B, B, 0, stream>>>((const float4*)dst, (float4*)dst, nn);
    }
  }
}